// Round 1
// baseline (4768.392 us; speedup 1.0000x reference)
//
#include <hip/hip_runtime.h>
#include <hip/hip_bf16.h>
#include <stdint.h>

#define B_  128
#define T_  512
#define H_  1024
#define E_  1024
#define NC_ 10
#define NT_ (B_*T_)   // 65536

typedef __attribute__((ext_vector_type(8))) short  short8;
typedef __attribute__((ext_vector_type(4))) float  f32x4;

static __device__ __forceinline__ float bf2f(ushort u){
  union { uint u; float f; } v; v.u = ((uint)u) << 16; return v.f;
}
static __device__ __forceinline__ ushort f2bf(float f){
  union { float f; uint u; } v; v.f = f;
  uint u = v.u;
  uint lsb = (u >> 16) & 1u;
  u += 0x7fffu + lsb;          // round-to-nearest-even
  return (ushort)(u >> 16);
}

// async global->LDS, 16B per lane. dst must be wave-uniform; HW adds lane*16.
#define ASYNC_COPY16(gsrc, ldsdst) \
  __builtin_amdgcn_global_load_lds((const __attribute__((address_space(1))) uint32_t*)(gsrc), \
                                   (__attribute__((address_space(3))) uint32_t*)(ldsdst), 16, 0, 0)

// ---------------- alive[t] = cumprod(colsum(x) != 0) ----------------
__global__ __launch_bounds__(512) void k_alive(const int* __restrict__ x,
                                               float* __restrict__ alive,
                                               float* __restrict__ aliveSum){
  __shared__ float fl[T_];
  int t = threadIdx.x;
  int s = 0;
  for (int b = 0; b < B_; ++b) s += x[b*T_ + t];
  fl[t] = (s != 0) ? 1.f : 0.f;
  __syncthreads();
  if (t == 0){
    float run = 1.f, sum = 0.f;
    for (int i = 0; i < T_; ++i){ run *= fl[i]; alive[i] = run; sum += run; }
    aliveSum[0] = sum;
  }
}

// ---------------- weight conversion: Wc -> bf16 (stride 2048), Wg h-part -> padded [16][1024] ----------------
__global__ __launch_bounds__(256) void k_convW(const float* __restrict__ Wc,
                                               const float* __restrict__ Wg,
                                               ushort* __restrict__ Wcb,
                                               ushort* __restrict__ Wgp){
  int idx = blockIdx.x*256 + threadIdx.x;
  if (idx < 1024*2048) Wcb[idx] = f2bf(Wc[idx]);
  if (idx < 16*1024){
    int j = idx >> 10, k = idx & 1023;
    float v = (j < 3) ? Wg[j*2048 + 1024 + k] : 0.f;
    Wgp[idx] = f2bf(v);
  }
}

// ---------------- gather + bf16 convert: XB[n][k] = bf16(embed[x[n]][k]) ----------------
__global__ __launch_bounds__(256) void k_gather(const int* __restrict__ x,
                                                const float* __restrict__ embed,
                                                ushort* __restrict__ XB){
  size_t g = (size_t)blockIdx.x*256 + threadIdx.x;
  const size_t total = (size_t)NT_ * 128;   // 8-element chunks
  for (; g < total; g += (size_t)gridDim.x*256){
    size_t row = g >> 7;
    int cj = (int)(g & 127) * 8;
    int tok = x[row];
    const float* src = embed + (size_t)tok*1024 + cj;
    float4 v0 = *(const float4*)src;
    float4 v1 = *(const float4*)(src + 4);
    uint4 o;
    o.x = (uint)f2bf(v0.x) | ((uint)f2bf(v0.y) << 16);
    o.y = (uint)f2bf(v0.z) | ((uint)f2bf(v0.w) << 16);
    o.z = (uint)f2bf(v1.x) | ((uint)f2bf(v1.y) << 16);
    o.w = (uint)f2bf(v1.z) | ((uint)f2bf(v1.w) << 16);
    *(uint4*)&XB[g*8] = o;
  }
}

// ---------------- big GEMM: A[n][o] = bf16( sum_k XB[n][k]*Wcb[o][k] + bc[o] ) ----------------
// m97-style: BM=BN=128, BK=64, 4 waves (2x2), global_load_lds width 16.
__global__ __launch_bounds__(256) void k_gemmA(const ushort* __restrict__ XB,
                                               const ushort* __restrict__ Wcb,
                                               const float* __restrict__ bc,
                                               ushort* __restrict__ A){
  __shared__ ushort As[128*64];
  __shared__ ushort Bs[128*64];
  const int bx = blockIdx.x;
  const int nt = bx & 7, mt = bx >> 3;
  const int tid = threadIdx.x, w = tid >> 6, l = tid & 63;
  const int wm = w >> 1, wn = w & 1;
  f32x4 acc[4][4];
  #pragma unroll
  for (int i = 0; i < 4; ++i)
    #pragma unroll
    for (int j = 0; j < 4; ++j) acc[i][j] = (f32x4){0.f,0.f,0.f,0.f};

  const int lrow = l >> 3, lcol = (l & 7) * 8;
  for (int kt = 0; kt < 16; ++kt){
    #pragma unroll
    for (int i = 0; i < 4; ++i){
      int cc = i*4 + w;
      const ushort* ga = XB  + (size_t)(mt*128 + cc*8 + lrow)*1024 + kt*64 + lcol;
      ASYNC_COPY16(ga, (char*)As + cc*1024);
      const ushort* gb = Wcb + (size_t)(nt*128 + cc*8 + lrow)*2048 + kt*64 + lcol;
      ASYNC_COPY16(gb, (char*)Bs + cc*1024);
    }
    __syncthreads();
    #pragma unroll
    for (int ks = 0; ks < 2; ++ks){
      short8 a[4], b[4];
      #pragma unroll
      for (int mi = 0; mi < 4; ++mi)
        a[mi] = *(const short8*)&As[(wm*64 + mi*16 + (l & 15))*64 + ks*32 + (l >> 4)*8];
      #pragma unroll
      for (int ni = 0; ni < 4; ++ni)
        b[ni] = *(const short8*)&Bs[(wn*64 + ni*16 + (l & 15))*64 + ks*32 + (l >> 4)*8];
      #pragma unroll
      for (int mi = 0; mi < 4; ++mi)
        #pragma unroll
        for (int ni = 0; ni < 4; ++ni)
          acc[mi][ni] = __builtin_amdgcn_mfma_f32_16x16x32_bf16(a[mi], b[ni], acc[mi][ni], 0, 0, 0);
    }
    __syncthreads();
  }
  const int col0 = nt*128 + wn*64;
  const int row0 = mt*128 + wm*64;
  #pragma unroll
  for (int ni = 0; ni < 4; ++ni){
    int col = col0 + ni*16 + (l & 15);
    float bias = bc[col];
    #pragma unroll
    for (int mi = 0; mi < 4; ++mi)
      #pragma unroll
      for (int r = 0; r < 4; ++r){
        int row = row0 + mi*16 + (l >> 4)*4 + r;
        A[(size_t)row*1024 + col] = f2bf(acc[mi][ni][r] + bias);
      }
  }
}

// ---------------- gate x-part: G[n][j] = sum_k XB[n][k]*Wg[j][k] + bg[j], j=0..2 ----------------
__global__ __launch_bounds__(256) void k_gateG(const ushort* __restrict__ XB,
                                               const float* __restrict__ Wg,
                                               const float* __restrict__ bgv,
                                               float* __restrict__ G){
  int tid = threadIdx.x, w = tid >> 6, l = tid & 63;
  size_t n = (size_t)blockIdx.x*4 + w;
  const ushort* xr = XB + n*1024;
  int k0 = l * 16;
  float s[3] = {0.f, 0.f, 0.f};
  #pragma unroll
  for (int h = 0; h < 2; ++h){
    short8 xv = *(const short8*)&xr[k0 + h*8];
    float xf[8];
    #pragma unroll
    for (int e = 0; e < 8; ++e) xf[e] = bf2f((ushort)xv[e]);
    #pragma unroll
    for (int j = 0; j < 3; ++j){
      const float* wr = Wg + (size_t)j*2048 + k0 + h*8;
      #pragma unroll
      for (int e = 0; e < 8; ++e) s[j] += xf[e] * wr[e];
    }
  }
  #pragma unroll
  for (int j = 0; j < 3; ++j){
    float v = s[j];
    for (int off = 32; off; off >>= 1) v += __shfl_xor(v, off, 64);
    if (l == 0) G[n*3 + j] = v + bgv[j];
  }
}

// ---------------- one recurrence step ----------------
// grid 128 = 8 batch-groups(16 rows) x 16 out-chunks(64 cols), 256 thr (4 waves, K split 4x256)
__global__ __launch_bounds__(256) void k_step(const ushort* __restrict__ Whh,   // = Wcb + 1024, row stride 2048
                                              const ushort* __restrict__ Wgp,   // [16][1024] padded gate h-weights
                                              const ushort* __restrict__ A,
                                              const float* __restrict__ G,
                                              const float* __restrict__ alive,
                                              const ushort* __restrict__ hprev,
                                              ushort* __restrict__ hnext,
                                              float* __restrict__ hsum,
                                              int t){
  __shared__ ushort hsm[16*1024];     // 32KB: h rows for this batch-group
  __shared__ float  upart[4][16*64];  // 16KB: per-wave K-partial of u
  __shared__ float  gpart[4][16*16];  // 4KB : per-wave K-partial of gate pre-acts
  const int bg = blockIdx.x >> 4, oc = blockIdx.x & 15;
  const int tid = threadIdx.x, w = tid >> 6, l = tid & 63;

  // stage h[bg*16 .. +16][0..1024) -> LDS (contiguous 32KB region)
  const ushort* hreg = hprev + (size_t)bg*16*1024;
  #pragma unroll
  for (int i = 0; i < 8; ++i){
    int cc = i*4 + w;
    ASYNC_COPY16(hreg + cc*512 + l*8, (char*)hsm + cc*1024);
  }
  __syncthreads();

  const int k0 = w * 256;
  const int lr = l & 15, lk = (l >> 4) * 8;
  f32x4 uacc[4]; f32x4 gacc = (f32x4){0.f,0.f,0.f,0.f};
  #pragma unroll
  for (int ni = 0; ni < 4; ++ni) uacc[ni] = (f32x4){0.f,0.f,0.f,0.f};

  #pragma unroll
  for (int ks = 0; ks < 8; ++ks){
    int kk = k0 + ks*32 + lk;
    short8 a = *(const short8*)&hsm[lr*1024 + kk];
    #pragma unroll
    for (int ni = 0; ni < 4; ++ni){
      short8 b = *(const short8*)&Whh[(size_t)(oc*64 + ni*16 + lr)*2048 + kk];
      uacc[ni] = __builtin_amdgcn_mfma_f32_16x16x32_bf16(a, b, uacc[ni], 0, 0, 0);
    }
    short8 bgf = *(const short8*)&Wgp[(size_t)lr*1024 + kk];
    gacc = __builtin_amdgcn_mfma_f32_16x16x32_bf16(a, bgf, gacc, 0, 0, 0);
  }
  #pragma unroll
  for (int ni = 0; ni < 4; ++ni)
    #pragma unroll
    for (int r = 0; r < 4; ++r)
      upart[w][((l >> 4)*4 + r)*64 + ni*16 + lr] = uacc[ni][r];
  #pragma unroll
  for (int r = 0; r < 4; ++r)
    gpart[w][((l >> 4)*4 + r)*16 + lr] = gacc[r];
  __syncthreads();

  // epilogue: thread -> row r (0..15), cols c0..c0+3
  const int r = tid >> 4, c0 = (tid & 15) * 4;
  const int b = bg*16 + r;
  const size_t n = (size_t)b*T_ + t;
  float g0 = G[n*3+0] + gpart[0][r*16+0] + gpart[1][r*16+0] + gpart[2][r*16+0] + gpart[3][r*16+0];
  float g2 = G[n*3+2] + gpart[0][r*16+2] + gpart[1][r*16+2] + gpart[2][r*16+2] + gpart[3][r*16+2];
  float gi = 1.f / (1.f + expf(-g0));
  float go = 1.f / (1.f + expf(-g2));
  float au = alive[t];
  const int o0 = oc*64 + c0;
  const ushort* Ap = A + n*1024 + o0;
  float*  hp = hsum + (size_t)b*1024 + o0;
  float4  hv = *(float4*)hp;
  ushort4 ho;
  float hn[4];
  #pragma unroll
  for (int j = 0; j < 4; ++j){
    float u = upart[0][r*64 + c0 + j] + upart[1][r*64 + c0 + j]
            + upart[2][r*64 + c0 + j] + upart[3][r*64 + c0 + j];
    float pre = bf2f(Ap[j]) + u;
    hn[j] = go * tanhf(gi * tanhf(pre));
  }
  hv.x += au*hn[0]; hv.y += au*hn[1]; hv.z += au*hn[2]; hv.w += au*hn[3];
  *(float4*)hp = hv;
  ho.x = f2bf(hn[0]); ho.y = f2bf(hn[1]); ho.z = f2bf(hn[2]); ho.w = f2bf(hn[3]);
  *(ushort4*)&hnext[(size_t)b*1024 + o0] = ho;
}

// ---------------- output: out[b][c] = dot(hsum[b], Wo[c]) / aliveSum + bo[c] ----------------
__global__ __launch_bounds__(256) void k_out(const float* __restrict__ hsum,
                                             const float* __restrict__ Wo,
                                             const float* __restrict__ bo,
                                             const float* __restrict__ aliveSum,
                                             float* __restrict__ out){
  __shared__ float accs[NC_];
  int b = blockIdx.x, tid = threadIdx.x;
  if (tid < NC_) accs[tid] = 0.f;
  __syncthreads();
  int k0 = tid * 4;
  float4 hv = *(const float4*)&hsum[(size_t)b*1024 + k0];
  float part[NC_];
  #pragma unroll
  for (int c = 0; c < NC_; ++c){
    const float* wr = Wo + (size_t)c*1024 + k0;
    part[c] = hv.x*wr[0] + hv.y*wr[1] + hv.z*wr[2] + hv.w*wr[3];
  }
  #pragma unroll
  for (int c = 0; c < NC_; ++c){
    float v = part[c];
    for (int off = 32; off; off >>= 1) v += __shfl_xor(v, off, 64);
    if ((tid & 63) == 0) atomicAdd(&accs[c], v);
  }
  __syncthreads();
  if (tid < NC_) out[b*NC_ + tid] = accs[tid] / aliveSum[0] + bo[tid];
}

extern "C" void kernel_launch(void* const* d_in, const int* in_sizes, int n_in,
                              void* d_out, int out_size, void* d_ws, size_t ws_size,
                              hipStream_t stream){
  const int*   x     = (const int*)  d_in[0];
  const float* embed = (const float*)d_in[1];
  const float* Wg    = (const float*)d_in[2];
  const float* bg    = (const float*)d_in[3];
  const float* Wc    = (const float*)d_in[4];
  const float* bc    = (const float*)d_in[5];
  const float* Wo    = (const float*)d_in[6];
  const float* bo    = (const float*)d_in[7];
  float* out = (float*)d_out;

  // workspace layout (~274.5 MB)
  char* p = (char*)d_ws;
  ushort* XB   = (ushort*)p;  p += (size_t)NT_*1024*2;     // 134.2MB
  ushort* A    = (ushort*)p;  p += (size_t)NT_*1024*2;     // 134.2MB
  ushort* Wcb  = (ushort*)p;  p += (size_t)1024*2048*2;    // 4MB
  ushort* Wgp  = (ushort*)p;  p += (size_t)16*1024*2;      // 32KB
  float*  G    = (float*)p;   p += (size_t)NT_*3*4;        // 786KB
  ushort* hbuf = (ushort*)p;  p += (size_t)2*B_*H_*2;      // 512KB
  float*  hsum = (float*)p;   p += (size_t)B_*H_*4;        // 512KB
  float*  alive= (float*)p;   p += (size_t)T_*4;
  float*  aliveSum = (float*)p; p += 256;

  (void)ws_size; (void)in_sizes; (void)n_in; (void)out_size;

  hipMemsetAsync(hbuf, 0, (size_t)B_*H_*2, stream);   // h0 = 0 (buffer slot 0)
  hipMemsetAsync(hsum, 0, (size_t)B_*H_*4, stream);

  k_alive <<<1,    512, 0, stream>>>(x, alive, aliveSum);
  k_convW <<<8192, 256, 0, stream>>>(Wc, Wg, Wcb, Wgp);
  k_gather<<<4096, 256, 0, stream>>>(x, embed, XB);
  k_gemmA <<<4096, 256, 0, stream>>>(XB, Wcb, bc, A);
  k_gateG <<<16384,256, 0, stream>>>(XB, Wg, bg, G);

  const ushort* Whh = Wcb + 1024;   // h-part of Wc, row stride 2048
  for (int t = 0; t < T_; ++t){
    const ushort* hp = hbuf + (size_t)(t & 1)*B_*H_;
    ushort*       hn = hbuf + (size_t)((t + 1) & 1)*B_*H_;
    k_step<<<128, 256, 0, stream>>>(Whh, Wgp, A, G, alive, hp, hn, hsum, t);
  }
  k_out<<<B_, 256, 0, stream>>>(hsum, Wo, bo, aliveSum, out);
}

// Round 3
// 2853.797 us; speedup vs baseline: 1.6709x; 1.6709x over previous
//
#include <hip/hip_runtime.h>
#include <hip/hip_bf16.h>
#include <stdint.h>

#define B_  128
#define T_  512
#define H_  1024
#define E_  1024
#define NC_ 10
#define NT_ (B_*T_)   // 65536

typedef __attribute__((ext_vector_type(8))) short  short8;
typedef __attribute__((ext_vector_type(4))) float  f32x4;

static __device__ __forceinline__ float bf2f(ushort u){
  union { uint u; float f; } v; v.u = ((uint)u) << 16; return v.f;
}
static __device__ __forceinline__ ushort f2bf(float f){
  union { float f; uint u; } v; v.f = f;
  uint u = v.u;
  uint lsb = (u >> 16) & 1u;
  u += 0x7fffu + lsb;          // round-to-nearest-even
  return (ushort)(u >> 16);
}

// async global->LDS, 16B per lane. LDS dst wave-uniform; HW adds lane*16. Global src per-lane.
#define ASYNC_COPY16(gsrc, ldsdst) \
  __builtin_amdgcn_global_load_lds((const __attribute__((address_space(1))) uint32_t*)(gsrc), \
                                   (__attribute__((address_space(3))) uint32_t*)(ldsdst), 16, 0, 0)

// ---------------- alive[t] = cumprod(colsum(x) != 0) ----------------
__global__ __launch_bounds__(512) void k_alive(const int* __restrict__ x,
                                               float* __restrict__ alive,
                                               float* __restrict__ aliveSum){
  __shared__ float fl[T_];
  int t = threadIdx.x;
  int s = 0;
  for (int b = 0; b < B_; ++b) s += x[b*T_ + t];
  fl[t] = (s != 0) ? 1.f : 0.f;
  __syncthreads();
  if (t == 0){
    float run = 1.f, sum = 0.f;
    for (int i = 0; i < T_; ++i){ run *= fl[i]; alive[i] = run; sum += run; }
    aliveSum[0] = sum;
  }
}

// ---------------- weight conversion: Wc -> bf16 (stride 2048) ----------------
__global__ __launch_bounds__(256) void k_convW(const float* __restrict__ Wc,
                                               ushort* __restrict__ Wcb){
  int idx = blockIdx.x*256 + threadIdx.x;
  if (idx < 1024*2048) Wcb[idx] = f2bf(Wc[idx]);
}

// ---------------- gather + bf16 convert: XB[n][k] = bf16(embed[x[n]][k]) ----------------
__global__ __launch_bounds__(256) void k_gather(const int* __restrict__ x,
                                                const float* __restrict__ embed,
                                                ushort* __restrict__ XB){
  size_t g = (size_t)blockIdx.x*256 + threadIdx.x;
  const size_t total = (size_t)NT_ * 128;   // 8-element chunks
  for (; g < total; g += (size_t)gridDim.x*256){
    size_t row = g >> 7;
    int cj = (int)(g & 127) * 8;
    int tok = x[row];
    const float* src = embed + (size_t)tok*1024 + cj;
    float4 v0 = *(const float4*)src;
    float4 v1 = *(const float4*)(src + 4);
    uint4 o;
    o.x = (uint)f2bf(v0.x) | ((uint)f2bf(v0.y) << 16);
    o.y = (uint)f2bf(v0.z) | ((uint)f2bf(v0.w) << 16);
    o.z = (uint)f2bf(v1.x) | ((uint)f2bf(v1.y) << 16);
    o.w = (uint)f2bf(v1.z) | ((uint)f2bf(v1.w) << 16);
    *(uint4*)&XB[g*8] = o;
  }
}

// ---------------- big GEMM: A2[t][b][o] = bf16( sum_k XB[n][k]*Wcb[o][k] + bc[o] ), n=b*T+t ----------------
__global__ __launch_bounds__(256) void k_gemmA(const ushort* __restrict__ XB,
                                               const ushort* __restrict__ Wcb,
                                               const float* __restrict__ bc,
                                               ushort* __restrict__ A2){
  __shared__ ushort As[128*64];
  __shared__ ushort Bs[128*64];
  const int bx = blockIdx.x;
  const int nt = bx & 7, mt = bx >> 3;
  const int tid = threadIdx.x, w = tid >> 6, l = tid & 63;
  const int wm = w >> 1, wn = w & 1;
  f32x4 acc[4][4];
  #pragma unroll
  for (int i = 0; i < 4; ++i)
    #pragma unroll
    for (int j = 0; j < 4; ++j) acc[i][j] = (f32x4){0.f,0.f,0.f,0.f};

  const int lrow = l >> 3, lcol = (l & 7) * 8;
  for (int kt = 0; kt < 16; ++kt){
    #pragma unroll
    for (int i = 0; i < 4; ++i){
      int cc = i*4 + w;
      const ushort* ga = XB  + (size_t)(mt*128 + cc*8 + lrow)*1024 + kt*64 + lcol;
      ASYNC_COPY16(ga, (char*)As + cc*1024);
      const ushort* gb = Wcb + (size_t)(nt*128 + cc*8 + lrow)*2048 + kt*64 + lcol;
      ASYNC_COPY16(gb, (char*)Bs + cc*1024);
    }
    __syncthreads();
    #pragma unroll
    for (int ks = 0; ks < 2; ++ks){
      short8 a[4], b[4];
      #pragma unroll
      for (int mi = 0; mi < 4; ++mi)
        a[mi] = *(const short8*)&As[(wm*64 + mi*16 + (l & 15))*64 + ks*32 + (l >> 4)*8];
      #pragma unroll
      for (int ni = 0; ni < 4; ++ni)
        b[ni] = *(const short8*)&Bs[(wn*64 + ni*16 + (l & 15))*64 + ks*32 + (l >> 4)*8];
      #pragma unroll
      for (int mi = 0; mi < 4; ++mi)
        #pragma unroll
        for (int ni = 0; ni < 4; ++ni)
          acc[mi][ni] = __builtin_amdgcn_mfma_f32_16x16x32_bf16(a[mi], b[ni], acc[mi][ni], 0, 0, 0);
    }
    __syncthreads();
  }
  const int col0 = nt*128 + wn*64;
  const int row0 = mt*128 + wm*64;
  #pragma unroll
  for (int ni = 0; ni < 4; ++ni){
    int col = col0 + ni*16 + (l & 15);
    float bias = bc[col];
    #pragma unroll
    for (int mi = 0; mi < 4; ++mi)
      #pragma unroll
      for (int r = 0; r < 4; ++r){
        int row = row0 + mi*16 + (l >> 4)*4 + r;   // n = b*T + t
        int b_i = row >> 9, t_i = row & 511;
        A2[((size_t)t_i*B_ + b_i)*1024 + col] = f2bf(acc[mi][ni][r] + bias);
      }
  }
}

// ---------------- gate x-part: G0/G2[t*B+b] = sum_k XB[n][k]*Wg[j][k] + bg[j], j in {0,2} ----------------
__global__ __launch_bounds__(256) void k_gateG(const ushort* __restrict__ XB,
                                               const float* __restrict__ Wg,
                                               const float* __restrict__ bgv,
                                               float* __restrict__ G0,
                                               float* __restrict__ G2){
  int tid = threadIdx.x, w = tid >> 6, l = tid & 63;
  size_t n = (size_t)blockIdx.x*4 + w;
  const ushort* xr = XB + n*1024;
  int k0 = l * 16;
  float s0 = 0.f, s2 = 0.f;
  #pragma unroll
  for (int h = 0; h < 2; ++h){
    short8 xv = *(const short8*)&xr[k0 + h*8];
    #pragma unroll
    for (int e = 0; e < 8; ++e){
      float xf = bf2f((ushort)xv[e]);
      s0 += xf * Wg[(size_t)0*2048 + k0 + h*8 + e];
      s2 += xf * Wg[(size_t)2*2048 + k0 + h*8 + e];
    }
  }
  for (int off = 32; off; off >>= 1){ s0 += __shfl_xor(s0, off, 64); s2 += __shfl_xor(s2, off, 64); }
  if (l == 0){
    int b_i = (int)(n >> 9), t_i = (int)(n & 511);
    G0[(size_t)t_i*B_ + b_i] = s0 + bgv[0];
    G2[(size_t)t_i*B_ + b_i] = s2 + bgv[2];
  }
}

// ---------------- hang-proof flag barrier ----------------
// flags: 32 slots (64B apart) per group. Writer WG stores its slot = target.
// Wave 0 polls all 32 slots (relaxed agent atomic loads), bounded; on timeout
// sets `dead` so every later barrier is a no-op (wrong result, but no GPU wedge).
static __device__ __forceinline__ void gbar(uint* flags, uint* dead, int oc, uint target){
  __syncthreads();   // all this-WG h stores drained (vmcnt0 before s_barrier)
  const int tid = threadIdx.x;
  if (tid == 0)
    __hip_atomic_store(&flags[oc*16], target, __ATOMIC_RELAXED, __HIP_MEMORY_SCOPE_AGENT);
  if (tid < 64){
    if (!__hip_atomic_load(dead, __ATOMIC_RELAXED, __HIP_MEMORY_SCOPE_AGENT)){
      uint it = 0;
      while (true){
        uint v = (tid < 32) ? __hip_atomic_load(&flags[tid*16], __ATOMIC_RELAXED, __HIP_MEMORY_SCOPE_AGENT)
                            : target;
        if (__all((int)(v >= target))) break;
        if ((++it & 1023u) == 0u){
          if (__hip_atomic_load(dead, __ATOMIC_RELAXED, __HIP_MEMORY_SCOPE_AGENT)) break;
          if (it > (1u << 21)){
            if (tid == 0) __hip_atomic_store(dead, 1u, __ATOMIC_RELAXED, __HIP_MEMORY_SCOPE_AGENT);
            break;
          }
        }
        __builtin_amdgcn_s_sleep(2);
      }
    }
    __builtin_amdgcn_fence(__ATOMIC_ACQUIRE, "agent");  // inv L1/L2 before re-reading h
  }
  __syncthreads();
}

// ---------------- persistent recurrence ----------------
// 256 WGs: bg = blk&7 (XCD-local batch-group of 16 rows), oc = blk>>3 (32 out cols).
// 113KB LDS forces 1 WG/CU; grid==256==#CUs => co-resident (plain launch, no coop API).
// Whh slice + gate weights LDS-resident for all 512 steps; h transits IF via
// relaxed agent atomic stores (write-through, no wbl2 needed); hsum in registers.
__global__ __launch_bounds__(256, 1) void k_recur(const ushort* __restrict__ Wcb,
                                                  const float*  __restrict__ Wg,
                                                  const ushort* __restrict__ A2,
                                                  const float*  __restrict__ G0,
                                                  const float*  __restrict__ G2,
                                                  const float*  __restrict__ alive,
                                                  ushort* __restrict__ hglob,   // [2][B][1024]
                                                  float*  __restrict__ hsum,    // [B][1024]
                                                  uint*   __restrict__ bar){    // flags[8][512] + dead
  __shared__ ushort WhhS[32*1024];      // 64KB, XOR-swizzled rows (out-cols)
  __shared__ ushort hS[16*1024];        // 32KB, XOR-swizzled rows (batch)
  __shared__ float  WgS[2*1024];        // 8KB  (gate rows 0,2; h-part, f32)
  __shared__ float  upart[4][16][34];   // 8.5KB cross-wave K-partials

  const int blk = blockIdx.x;
  const int bg = blk & 7, oc = blk >> 3;
  const int tid = threadIdx.x, w = tid >> 6, l = tid & 63;

  // ---- prologue: Whh slice -> LDS (swizzled write) ----
  #pragma unroll
  for (int it = 0; it < 16; ++it){
    int ch = it*256 + tid;            // 4096 chunks of 16B
    int ci = ch >> 7;                 // local col 0..31
    int kb = (ch & 127) * 16;         // byte in 2048B row
    const char* src = (const char*)Wcb + (((size_t)(oc*32 + ci)*2048 + 1024) * 2) + kb;
    uint4 v = *(const uint4*)src;
    *(uint4*)((char*)WhhS + ci*2048 + (kb ^ ((ci & 7) << 4))) = v;
  }
  #pragma unroll
  for (int it = 0; it < 8; ++it){
    int idx = it*256 + tid;           // 0..2047
    int j = idx >> 10;                // 0 -> gate0, 1 -> gate2
    int k = idx & 1023;
    WgS[idx] = Wg[(size_t)(j*2)*2048 + 1024 + k];
  }
  __syncthreads();

  const int r_ep = tid >> 4;                 // epilogue row 0..15 (== w*4 + (l>>4))
  const int c0   = (tid & 15) * 2;           // epilogue col pair
  const int b_ep = bg*16 + r_ep;
  const int rg   = w*4 + (l >> 4);           // gate row this 16-lane group handles
  const int lr   = l & 15, lk = (l >> 4) * 8;
  float hs0 = 0.f, hs1 = 0.f;

  uint* flags = bar + bg*512;
  uint* dead  = bar + 8*512;

  for (int t = 0; t < T_; ++t){
    // ---- stage h slab (pre-swizzled global source -> linear LDS) ----
    const ushort* hprev = hglob + (size_t)(t & 1)*B_*H_ + (size_t)bg*16*1024;
    #pragma unroll
    for (int j = 0; j < 8; ++j){
      int seg = w*8 + j;              // 32 segments of 1KB
      int ri = seg >> 1, hf = seg & 1;
      const ushort* src = hprev + (size_t)ri*1024 + hf*512 + ((l ^ (ri & 7)) * 8);
      ASYNC_COPY16(src, (char*)hS + seg*1024);
    }
    // ---- early independent loads (read-only data) ----
    uint av = *(const uint*)&A2[((size_t)t*B_ + b_ep)*1024 + oc*32 + c0];
    float a0 = bf2f((ushort)(av & 0xffffu));
    float a1 = bf2f((ushort)(av >> 16));
    float gx0 = G0[(size_t)t*B_ + bg*16 + rg];
    float gx2 = G2[(size_t)t*B_ + bg*16 + rg];
    float au  = alive[t];
    __syncthreads();                  // hS ready (drains vmcnt)

    // ---- gates (VALU): row rg, lane covers k = (l&15)*8 + jj*128 .. +8 ----
    float s0 = 0.f, s2 = 0.f;
    #pragma unroll
    for (int jj = 0; jj < 8; ++jj){
      int ke = (l & 15)*8 + jj*128;
      int kb = ke*2;
      short8 hv = *(const short8*)((const char*)hS + rg*2048 + (kb ^ ((rg & 7) << 4)));
      float4 w0a = *(const float4*)&WgS[ke];
      float4 w0b = *(const float4*)&WgS[ke + 4];
      float4 w2a = *(const float4*)&WgS[1024 + ke];
      float4 w2b = *(const float4*)&WgS[1024 + ke + 4];
      float h0 = bf2f((ushort)hv[0]), h1 = bf2f((ushort)hv[1]);
      float h2 = bf2f((ushort)hv[2]), h3 = bf2f((ushort)hv[3]);
      float h4 = bf2f((ushort)hv[4]), h5 = bf2f((ushort)hv[5]);
      float h6 = bf2f((ushort)hv[6]), h7 = bf2f((ushort)hv[7]);
      s0 += h0*w0a.x + h1*w0a.y + h2*w0a.z + h3*w0a.w
          + h4*w0b.x + h5*w0b.y + h6*w0b.z + h7*w0b.w;
      s2 += h0*w2a.x + h1*w2a.y + h2*w2a.z + h3*w2a.w
          + h4*w2b.x + h5*w2b.y + h6*w2b.z + h7*w2b.w;
    }
    #pragma unroll
    for (int off = 8; off; off >>= 1){ s0 += __shfl_xor(s0, off, 64); s2 += __shfl_xor(s2, off, 64); }
    float gi = 1.f / (1.f + expf(-(gx0 + s0)));
    float go = 1.f / (1.f + expf(-(gx2 + s2)));

    // ---- u = h @ Whh_slice^T (MFMA, K split across waves) ----
    f32x4 uacc0 = (f32x4){0.f,0.f,0.f,0.f};
    f32x4 uacc1 = (f32x4){0.f,0.f,0.f,0.f};
    #pragma unroll
    for (int ks = 0; ks < 8; ++ks){
      int kb = (w*256 + ks*32 + lk) * 2;
      int swz = kb ^ ((lr & 7) << 4);
      short8 a  = *(const short8*)((const char*)hS   + lr*2048 + swz);
      short8 b0 = *(const short8*)((const char*)WhhS + lr*2048 + swz);
      short8 b1 = *(const short8*)((const char*)WhhS + (16 + lr)*2048 + swz);
      uacc0 = __builtin_amdgcn_mfma_f32_16x16x32_bf16(a, b0, uacc0, 0, 0, 0);
      uacc1 = __builtin_amdgcn_mfma_f32_16x16x32_bf16(a, b1, uacc1, 0, 0, 0);
    }
    #pragma unroll
    for (int r4 = 0; r4 < 4; ++r4){
      int m = (l >> 4)*4 + r4;
      upart[w][m][lr]      = uacc0[r4];
      upart[w][m][16 + lr] = uacc1[r4];
    }
    __syncthreads();

    // ---- epilogue: 2 outputs per thread ----
    float u0 = upart[0][r_ep][c0]   + upart[1][r_ep][c0]   + upart[2][r_ep][c0]   + upart[3][r_ep][c0];
    float u1 = upart[0][r_ep][c0+1] + upart[1][r_ep][c0+1] + upart[2][r_ep][c0+1] + upart[3][r_ep][c0+1];
    float hn0 = go * tanhf(gi * tanhf(a0 + u0));
    float hn1 = go * tanhf(gi * tanhf(a1 + u1));
    hs0 += au * hn0;
    hs1 += au * hn1;
    // write-through h store (agent-visible without any fence/wbl2)
    uint hv2 = (uint)f2bf(hn0) | ((uint)f2bf(hn1) << 16);
    uint* hdst = (uint*)&hglob[(size_t)((t + 1) & 1)*B_*H_ + (size_t)b_ep*1024 + oc*32 + c0];
    __hip_atomic_store(hdst, hv2, __ATOMIC_RELAXED, __HIP_MEMORY_SCOPE_AGENT);

    // ---- group barrier: 32 WGs of this batch-group ----
    gbar(flags, dead, oc, (uint)(t + 1));
  }

  hsum[(size_t)b_ep*1024 + oc*32 + c0]     = hs0;
  hsum[(size_t)b_ep*1024 + oc*32 + c0 + 1] = hs1;
}

// ---------------- output: out[b][c] = dot(hsum[b], Wo[c]) / aliveSum + bo[c] ----------------
__global__ __launch_bounds__(256) void k_out(const float* __restrict__ hsum,
                                             const float* __restrict__ Wo,
                                             const float* __restrict__ bo,
                                             const float* __restrict__ aliveSum,
                                             float* __restrict__ out){
  __shared__ float accs[NC_];
  int b = blockIdx.x, tid = threadIdx.x;
  if (tid < NC_) accs[tid] = 0.f;
  __syncthreads();
  int k0 = tid * 4;
  float4 hv = *(const float4*)&hsum[(size_t)b*1024 + k0];
  float part[NC_];
  #pragma unroll
  for (int c = 0; c < NC_; ++c){
    const float* wr = Wo + (size_t)c*1024 + k0;
    part[c] = hv.x*wr[0] + hv.y*wr[1] + hv.z*wr[2] + hv.w*wr[3];
  }
  #pragma unroll
  for (int c = 0; c < NC_; ++c){
    float v = part[c];
    for (int off = 32; off; off >>= 1) v += __shfl_xor(v, off, 64);
    if ((tid & 63) == 0) atomicAdd(&accs[c], v);
  }
  __syncthreads();
  if (tid < NC_) out[b*NC_ + tid] = accs[tid] / aliveSum[0] + bo[tid];
}

extern "C" void kernel_launch(void* const* d_in, const int* in_sizes, int n_in,
                              void* d_out, int out_size, void* d_ws, size_t ws_size,
                              hipStream_t stream){
  const int*   x     = (const int*)  d_in[0];
  const float* embed = (const float*)d_in[1];
  const float* Wg    = (const float*)d_in[2];
  const float* bg    = (const float*)d_in[3];
  const float* Wc    = (const float*)d_in[4];
  const float* bc    = (const float*)d_in[5];
  const float* Wo    = (const float*)d_in[6];
  const float* bo    = (const float*)d_in[7];
  float* out = (float*)d_out;

  // workspace layout (~274 MB)
  char* p = (char*)d_ws;
  ushort* XB    = (ushort*)p;  p += (size_t)NT_*1024*2;     // 134.2MB
  ushort* A2    = (ushort*)p;  p += (size_t)NT_*1024*2;     // 134.2MB  [t][b][1024]
  ushort* Wcb   = (ushort*)p;  p += (size_t)1024*2048*2;    // 4MB
  float*  G0    = (float*)p;   p += (size_t)NT_*4;          // 256KB
  float*  G2    = (float*)p;   p += (size_t)NT_*4;          // 256KB
  ushort* hglob = (ushort*)p;  p += (size_t)2*B_*H_*2;      // 512KB
  float*  hsum  = (float*)p;   p += (size_t)B_*H_*4;        // 512KB
  float*  alive = (float*)p;   p += (size_t)T_*4;
  float*  aliveSum = (float*)p; p += 256;
  uint*   bar   = (uint*)p;    p += 32*1024;                // flags + dead

  (void)ws_size; (void)in_sizes; (void)n_in; (void)out_size;

  hipMemsetAsync(hglob, 0, (size_t)B_*H_*2, stream);   // h0 = 0 (buffer slot 0)
  hipMemsetAsync(bar,   0, 32*1024, stream);           // barrier flags + dead

  k_alive <<<1,    512, 0, stream>>>(x, alive, aliveSum);
  k_convW <<<8192, 256, 0, stream>>>(Wc, Wcb);
  k_gather<<<4096, 256, 0, stream>>>(x, embed, XB);
  k_gemmA <<<4096, 256, 0, stream>>>(XB, Wcb, bc, A2);
  k_gateG <<<16384,256, 0, stream>>>(XB, Wg, bg, G0, G2);

  k_recur<<<256, 256, 0, stream>>>(Wcb, Wg, A2, G0, G2, alive, hglob, hsum, bar);

  k_out<<<B_, 256, 0, stream>>>(hsum, Wo, bo, aliveSum, out);
}